// Round 4
// baseline (135.839 us; speedup 1.0000x reference)
//
#include <hip/hip_runtime.h>
#include <hip/hip_bf16.h>

// Problem constants (fixed: H=W=128, C=64, K=3, HID=256, OUT_C=3, scale=2)
#define H_IN 128
#define W_IN 128
#define C_IN 64
#define HID 256
#define OUT_C 3
#define OUT_W 256
#define NW 1728   // 3*3*64*3 weights per parity
#define PPW 8     // input pixels per wave in the einsum phase
#define NBLK 512
#define NPROD 27

__device__ __forceinline__ float rdlane(float v, int l) {
    return __int_as_float(__builtin_amdgcn_readlane(__float_as_int(v), l));
}

// ---------------------------------------------------------------------------
// Phase A (device fn): blocks 0..26 compute the 4-parity MLP weights -> wts.
// Block-local: h1 (regs) -> h2 (k2 matmul, LDS cross-wave reduce) -> k3 slice.
// ---------------------------------------------------------------------------
__device__ __forceinline__ void mlp_phase(
    const float* __restrict__ k1, const float* __restrict__ b1,
    const float* __restrict__ k2, const float* __restrict__ b2,
    const float* __restrict__ k3, const float* __restrict__ b3,
    float* __restrict__ wts, int bid, int tid)
{
    __shared__ float sPart[4][4][256];   // [wave][par][n]
    __shared__ float sH2[4][256];        // [par][n]
    const int lane = tid & 63;
    const int w    = tid >> 6;

    // h1 for this wave's m-slice (m = w*64+lane), 4 parities
    const int m = w * 64 + lane;
    const float k10 = k1[m], k11 = k1[HID + m], k12 = k1[2 * HID + m];
    const float b1m = b1[m];
    float h1r[4];
    h1r[0] = fmaxf(0.5f * k12 + b1m, 0.0f);
    h1r[1] = fmaxf(0.5f * k11 + 0.5f * k12 + b1m, 0.0f);
    h1r[2] = fmaxf(0.5f * k10 + 0.5f * k12 + b1m, 0.0f);
    h1r[3] = fmaxf(0.5f * k10 + 0.5f * k11 + 0.5f * k12 + b1m, 0.0f);

    // partial h2: wave w covers m in [64w,64w+64), cols 4*lane..+3, 4 parities
    float4 acc[4];
#pragma unroll
    for (int p = 0; p < 4; ++p) acc[p] = make_float4(0.f, 0.f, 0.f, 0.f);
    const float* k2p = k2 + (w * 64) * HID + 4 * lane;
#pragma unroll
    for (int i = 0; i < 64; ++i) {
        const float4 kv = *reinterpret_cast<const float4*>(k2p + i * HID);
#pragma unroll
        for (int p = 0; p < 4; ++p) {
            const float hm = rdlane(h1r[p], i);
            acc[p].x = fmaf(hm, kv.x, acc[p].x);
            acc[p].y = fmaf(hm, kv.y, acc[p].y);
            acc[p].z = fmaf(hm, kv.z, acc[p].z);
            acc[p].w = fmaf(hm, kv.w, acc[p].w);
        }
    }
#pragma unroll
    for (int p = 0; p < 4; ++p)
        *reinterpret_cast<float4*>(&sPart[w][p][4 * lane]) = acc[p];
    __syncthreads();

    // reduce 4 waves -> h2 (relu)
    const float b2v = b2[tid];
#pragma unroll
    for (int p = 0; p < 4; ++p) {
        const float s = b2v + sPart[0][p][tid] + sPart[1][p][tid]
                      + sPart[2][p][tid] + sPart[3][p][tid];
        sH2[p][tid] = fmaxf(s, 0.0f);
    }
    __syncthreads();

    // this block's 64 k3 columns; wave w covers its m-range
    const int colbase = bid * 64;
    float h2r[4];
#pragma unroll
    for (int p = 0; p < 4; ++p) h2r[p] = sH2[p][w * 64 + lane];

    float a0 = 0.f, a1 = 0.f, a2 = 0.f, a3 = 0.f;
    const float* kp = k3 + (size_t)(w * 64) * NW + colbase + lane;
#pragma unroll
    for (int i = 0; i < 64; ++i) {
        const float kv = kp[(size_t)i * NW];
        a0 = fmaf(rdlane(h2r[0], i), kv, a0);
        a1 = fmaf(rdlane(h2r[1], i), kv, a1);
        a2 = fmaf(rdlane(h2r[2], i), kv, a2);
        a3 = fmaf(rdlane(h2r[3], i), kv, a3);
    }
    sPart[w][0][lane] = a0; sPart[w][1][lane] = a1;
    sPart[w][2][lane] = a2; sPart[w][3][lane] = a3;
    __syncthreads();

    const int p = tid >> 6, c = tid & 63;
    const int n = colbase + c;
    const float s = b3[n] + sPart[0][p][c] + sPart[1][p][c]
                  + sPart[2][p][c] + sPart[3][p][c];
    // n = ((pp*3+q)*64 + ch)*3 + o  ->  [par][o][pq][ch]
    const int o = n % 3;
    const int rest = n / 3;
    const int cch = rest & 63;
    const int pq = rest >> 6;
    wts[p * NW + (o * 9 + pq) * 64 + cch] = s;
}

// ---------------------------------------------------------------------------
// Phase C (device fn): the einsum. Wave = 4 parities x 16 c4-chunks, PPW
// pixels per wave. Feature-column ring buffer (3 loads/pixel). If WAIT, the
// first two columns are prefetched BEFORE the flag spin (overlaps phase A).
// ---------------------------------------------------------------------------
template <bool WAIT>
__device__ __forceinline__ void einsum_phase(
    const float* __restrict__ feat, const float* __restrict__ wts,
    float* __restrict__ out, int* flag, int bid, int tid)
{
    const int lane = tid & 63;
    const int w    = tid >> 6;
    const int gw   = bid * 4 + w;            // 0..2047
    const int iy   = gw >> 4;                // input row 0..127
    const int ix0  = (gw & 15) * PPW;        // input col base
    const int par  = lane >> 4;              // 0..3
    const int c4   = lane & 15;              // channel quad
    const int pi = par >> 1, pj = par & 1;

    const bool rv0 = iy > 0, rv2 = iy < H_IN - 1;
    const float4 fz = make_float4(0.f, 0.f, 0.f, 0.f);
    const float* frow0 = feat + ((iy - 1) * W_IN) * C_IN + c4 * 4;
    const float* frow1 = feat + ((iy    ) * W_IN) * C_IN + c4 * 4;
    const float* frow2 = feat + ((iy + 1) * W_IN) * C_IN + c4 * 4;

    float4 fc0[3], fc1[3], fc2[3];
    auto ldcol = [&](int cc, float4& a, float4& b, float4& c) {
        if ((unsigned)cc < (unsigned)W_IN) {
            a = rv0 ? *reinterpret_cast<const float4*>(frow0 + cc * C_IN) : fz;
            b =       *reinterpret_cast<const float4*>(frow1 + cc * C_IN);
            c = rv2 ? *reinterpret_cast<const float4*>(frow2 + cc * C_IN) : fz;
        } else { a = fz; b = fz; c = fz; }
    };
    // Prefetch the first two columns (overlaps producer wait below).
    ldcol(ix0 - 1, fc0[0], fc1[0], fc2[0]);
    ldcol(ix0,     fc0[1], fc1[1], fc2[1]);

    if (WAIT) {
        if (tid == 0) {
            int it = 0;
            while (__hip_atomic_load(flag, __ATOMIC_ACQUIRE,
                                     __HIP_MEMORY_SCOPE_AGENT) < NPROD
                   && it < (1 << 23)) {
                __builtin_amdgcn_s_sleep(2);
                ++it;
            }
        }
        __syncthreads();
        __threadfence();   // acquire: invalidate stale cache lines before wts reads
    }

    float4 wreg[3][9];
#pragma unroll
    for (int o = 0; o < 3; ++o)
#pragma unroll
        for (int pq = 0; pq < 9; ++pq)
            wreg[o][pq] = *reinterpret_cast<const float4*>(
                wts + ((par * 3 + o) * 9 + pq) * 64 + c4 * 4);

#pragma unroll
    for (int g = 0; g < PPW; ++g) {
        const int sNew = (g + 2) % 3;
        ldcol(ix0 + g + 1, fc0[sNew], fc1[sNew], fc2[sNew]);

        float acc0 = 0.f, acc1 = 0.f, acc2 = 0.f;
#pragma unroll
        for (int q = 0; q < 3; ++q) {
            const int s = (g + q) % 3;
            const float4 f0 = fc0[s], f1 = fc1[s], f2 = fc2[s];
            const int pq0 = q, pq1 = 3 + q, pq2 = 6 + q;
            acc0 = fmaf(f0.x, wreg[0][pq0].x, acc0);
            acc0 = fmaf(f0.y, wreg[0][pq0].y, acc0);
            acc0 = fmaf(f0.z, wreg[0][pq0].z, acc0);
            acc0 = fmaf(f0.w, wreg[0][pq0].w, acc0);
            acc1 = fmaf(f0.x, wreg[1][pq0].x, acc1);
            acc1 = fmaf(f0.y, wreg[1][pq0].y, acc1);
            acc1 = fmaf(f0.z, wreg[1][pq0].z, acc1);
            acc1 = fmaf(f0.w, wreg[1][pq0].w, acc1);
            acc2 = fmaf(f0.x, wreg[2][pq0].x, acc2);
            acc2 = fmaf(f0.y, wreg[2][pq0].y, acc2);
            acc2 = fmaf(f0.z, wreg[2][pq0].z, acc2);
            acc2 = fmaf(f0.w, wreg[2][pq0].w, acc2);

            acc0 = fmaf(f1.x, wreg[0][pq1].x, acc0);
            acc0 = fmaf(f1.y, wreg[0][pq1].y, acc0);
            acc0 = fmaf(f1.z, wreg[0][pq1].z, acc0);
            acc0 = fmaf(f1.w, wreg[0][pq1].w, acc0);
            acc1 = fmaf(f1.x, wreg[1][pq1].x, acc1);
            acc1 = fmaf(f1.y, wreg[1][pq1].y, acc1);
            acc1 = fmaf(f1.z, wreg[1][pq1].z, acc1);
            acc1 = fmaf(f1.w, wreg[1][pq1].w, acc1);
            acc2 = fmaf(f1.x, wreg[2][pq1].x, acc2);
            acc2 = fmaf(f1.y, wreg[2][pq1].y, acc2);
            acc2 = fmaf(f1.z, wreg[2][pq1].z, acc2);
            acc2 = fmaf(f1.w, wreg[2][pq1].w, acc2);

            acc0 = fmaf(f2.x, wreg[0][pq2].x, acc0);
            acc0 = fmaf(f2.y, wreg[0][pq2].y, acc0);
            acc0 = fmaf(f2.z, wreg[0][pq2].z, acc0);
            acc0 = fmaf(f2.w, wreg[0][pq2].w, acc0);
            acc1 = fmaf(f2.x, wreg[1][pq2].x, acc1);
            acc1 = fmaf(f2.y, wreg[1][pq2].y, acc1);
            acc1 = fmaf(f2.z, wreg[1][pq2].z, acc1);
            acc1 = fmaf(f2.w, wreg[1][pq2].w, acc1);
            acc2 = fmaf(f2.x, wreg[2][pq2].x, acc2);
            acc2 = fmaf(f2.y, wreg[2][pq2].y, acc2);
            acc2 = fmaf(f2.z, wreg[2][pq2].z, acc2);
            acc2 = fmaf(f2.w, wreg[2][pq2].w, acc2);
        }

        // 8-shuffle reduction over 16 lanes for 3 values
        acc0 += __shfl_xor(acc0, 1); acc0 += __shfl_xor(acc0, 2);
        acc1 += __shfl_xor(acc1, 1); acc1 += __shfl_xor(acc1, 2);
        acc2 += __shfl_xor(acc2, 1); acc2 += __shfl_xor(acc2, 2);
        const int j = c4 & 3;
        float v = (j == 0) ? acc0 : ((j == 1) ? acc1 : acc2);
        v += __shfl_xor(v, 4);
        v += __shfl_xor(v, 8);
        if (c4 < 3) {
            const int oy = 2 * iy + pi;
            const int ox = 2 * (ix0 + g) + pj;
            out[(oy * OUT_W + ox) * OUT_C + c4] = v;
        }
    }
}

// ===========================================================================
// Fused cooperative kernel: custom producer-flag barrier (NOT cg::sync).
// ===========================================================================
__global__ __launch_bounds__(256, 2) void fused_kernel(
    const float* __restrict__ feat,
    const float* __restrict__ k1, const float* __restrict__ b1,
    const float* __restrict__ k2, const float* __restrict__ b2,
    const float* __restrict__ k3, const float* __restrict__ b3,
    float* __restrict__ wts, int* flag, float* __restrict__ out)
{
    const int tid = threadIdx.x;
    const int bid = blockIdx.x;

    if (bid < NPROD) {
        mlp_phase(k1, b1, k2, b2, k3, b3, wts, bid, tid);
        __threadfence();                 // release this thread's wts stores
    }
    __syncthreads();
    if (bid < NPROD && tid == 0)
        __hip_atomic_fetch_add(flag, 1, __ATOMIC_RELEASE,
                               __HIP_MEMORY_SCOPE_AGENT);

    einsum_phase<true>(feat, wts, out, flag, bid, tid);
}

// ===========================================================================
// Non-cooperative fallback: 2 kernels.
// ===========================================================================
__global__ __launch_bounds__(256) void mlp_fb(
    const float* __restrict__ k1, const float* __restrict__ b1,
    const float* __restrict__ k2, const float* __restrict__ b2,
    const float* __restrict__ k3, const float* __restrict__ b3,
    float* __restrict__ wts)
{
    mlp_phase(k1, b1, k2, b2, k3, b3, wts, blockIdx.x, threadIdx.x);
}

__global__ __launch_bounds__(256) void upscale_fb(
    const float* __restrict__ feat, const float* __restrict__ wts,
    float* __restrict__ out)
{
    einsum_phase<false>(feat, wts, out, nullptr, blockIdx.x, threadIdx.x);
}

// ---------------------------------------------------------------------------
extern "C" void kernel_launch(void* const* d_in, const int* in_sizes, int n_in,
                              void* d_out, int out_size, void* d_ws, size_t ws_size,
                              hipStream_t stream)
{
    const float* feat = (const float*)d_in[0];
    const float* k1   = (const float*)d_in[1];
    const float* b1   = (const float*)d_in[2];
    const float* k2   = (const float*)d_in[3];
    const float* b2   = (const float*)d_in[4];
    const float* k3   = (const float*)d_in[5];
    const float* b3   = (const float*)d_in[6];
    float* out = (float*)d_out;
    float* ws  = (float*)d_ws;
    float* wts = ws;                         // 4*NW floats, [par][o][pq][c]
    int*   flag = (int*)(ws + 4 * NW);       // producer-done counter

    hipMemsetAsync(flag, 0, sizeof(int), stream);

    void* args[] = {(void*)&feat, (void*)&k1, (void*)&b1, (void*)&k2,
                    (void*)&b2, (void*)&k3, (void*)&b3, (void*)&wts,
                    (void*)&flag, (void*)&out};
    hipError_t err = hipLaunchCooperativeKernel(
        (const void*)fused_kernel, dim3(NBLK), dim3(256), args, 0, stream);
    if (err != hipSuccess) {
        mlp_fb<<<NPROD, 256, 0, stream>>>(k1, b1, k2, b2, k3, b3, wts);
        upscale_fb<<<NBLK, 256, 0, stream>>>(feat, wts, out);
    }
}